// Round 1
// baseline (51.483 us; speedup 1.0000x reference)
//
#include <hip/hip_runtime.h>

// 3x3 median filter, stride 1, reflect padding ("same"), NCHW fp32.
// Input: 32 x 3 x 512 x 512 fp32. Output: same shape.

#define IMG_H 512
#define IMG_W 512

// sort2: a <- min, b <- max
__device__ __forceinline__ void s2(float& a, float& b) {
    float t = fminf(a, b);
    b = fmaxf(a, b);
    a = t;
}

// Paeth 19-exchange median-of-9 network.
__device__ __forceinline__ float median9(float p0, float p1, float p2,
                                         float p3, float p4, float p5,
                                         float p6, float p7, float p8) {
    s2(p1, p2); s2(p4, p5); s2(p7, p8);
    s2(p0, p1); s2(p3, p4); s2(p6, p7);
    s2(p1, p2); s2(p4, p5); s2(p7, p8);
    s2(p0, p3); s2(p5, p8); s2(p4, p7);
    s2(p3, p6); s2(p1, p4); s2(p2, p5);
    s2(p4, p7); s2(p4, p2); s2(p6, p4);
    s2(p4, p2);
    return p4;
}

__global__ __launch_bounds__(256) void median3x3_kernel(
        const float* __restrict__ in, float* __restrict__ out, int nplanes) {
    const int THREADS_PER_ROW = IMG_W / 4;  // 128 quads per row
    int gid = blockIdx.x * blockDim.x + threadIdx.x;
    int row = gid / THREADS_PER_ROW;
    int xq  = (gid % THREADS_PER_ROW) * 4;   // first of 4 output columns
    int plane = row >> 9;                    // row / 512
    int y     = row & (IMG_H - 1);
    if (plane >= nplanes) return;

    const float* base = in + (size_t)plane * IMG_H * IMG_W;
    // reflect-pad row indices (pad=1): -1 -> 1, H -> H-2
    int ym = (y == 0)         ? 1         : y - 1;
    int yp = (y == IMG_H - 1) ? IMG_H - 2 : y + 1;
    const float* r0 = base + (size_t)ym * IMG_W;
    const float* r1 = base + (size_t)y  * IMG_W;
    const float* r2 = base + (size_t)yp * IMG_W;

    // reflect-pad column indices for the two edge taps
    int xm = (xq == 0)            ? 1         : xq - 1;      // col xq-1
    int xp = (xq + 4 == IMG_W)    ? IMG_W - 2 : xq + 4;      // col xq+4

    // aligned vector loads of the 4 central columns per row
    float4 a = *reinterpret_cast<const float4*>(r0 + xq);
    float4 b = *reinterpret_cast<const float4*>(r1 + xq);
    float4 c = *reinterpret_cast<const float4*>(r2 + xq);
    float aL = r0[xm], aR = r0[xp];
    float bL = r1[xm], bR = r1[xp];
    float cL = r2[xm], cR = r2[xp];

    // columns available per row: L, x, y, z, w, R  (xq-1 .. xq+4)
    float4 o;
    o.x = median9(aL,  a.x, a.y,  bL,  b.x, b.y,  cL,  c.x, c.y);
    o.y = median9(a.x, a.y, a.z,  b.x, b.y, b.z,  c.x, c.y, c.z);
    o.z = median9(a.y, a.z, a.w,  b.y, b.z, b.w,  c.y, c.z, c.w);
    o.w = median9(a.z, a.w, aR,   b.z, b.w, bR,   c.z, c.w, cR);

    float* orow = out + (size_t)plane * IMG_H * IMG_W + (size_t)y * IMG_W;
    *reinterpret_cast<float4*>(orow + xq) = o;
}

extern "C" void kernel_launch(void* const* d_in, const int* in_sizes, int n_in,
                              void* d_out, int out_size, void* d_ws, size_t ws_size,
                              hipStream_t stream) {
    const float* x = (const float*)d_in[0];
    float* out = (float*)d_out;
    int nplanes = in_sizes[0] / (IMG_H * IMG_W);   // 32*3 = 96

    int total_threads = nplanes * IMG_H * (IMG_W / 4);   // 6,291,456
    int block = 256;
    int grid = (total_threads + block - 1) / block;      // 24,576
    median3x3_kernel<<<grid, block, 0, stream>>>(x, out, nplanes);
}